// Round 5
// baseline (3514.557 us; speedup 1.0000x reference)
//
#include <hip/hip_runtime.h>
#include <math.h>

#define N_NODES 10000
#define N_EDGES 320000

// Source-bucketing: each node's edge list is stored bucket-contiguous by
// src/1250 (8 buckets). Concurrent waves traverse buckets in the same order,
// so the per-XCD L2 working set of gathered t1 rows is ~1/8 of the full
// 2.5 MB row array -> rows stay L2-resident within a step (kills the 3.6x
// cross-fabric fetch amplification seen in r1 persistent counters).
#define NBUCK 8
#define BUCK_DIV 1250   // N_NODES / NBUCK

// ---------------- setup kernels ----------------

__global__ void k_init(float* deg, int* cnt, int* fill, int n) {
    int i = blockIdx.x * blockDim.x + threadIdx.x;
    if (i < n) deg[i] = 0.f;
    if (i < n * NBUCK) { cnt[i] = 0; fill[i] = 0; }
}

__global__ void k_deg(const int* __restrict__ ei, const float* __restrict__ w,
                      float* deg, int E) {
    int e = blockIdx.x * blockDim.x + threadIdx.x;
    if (e < E) atomicAdd(&deg[ei[e]], w[e]);
}

__global__ void k_dis(float* deg, int n) {
    int i = blockIdx.x * blockDim.x + threadIdx.x;
    if (i < n) {
        float d = deg[i];
        deg[i] = (d > 0.f) ? (float)(1.0 / sqrt((double)d)) : 0.f;
    }
}

__global__ void k_norm(const int* __restrict__ ei, const float* __restrict__ w,
                       const float* __restrict__ dis, float* __restrict__ normw,
                       int* cnt, int E) {
    int e = blockIdx.x * blockDim.x + threadIdx.x;
    if (e < E) {
        int s = ei[e], d = ei[E + e];
        normw[e] = -dis[s] * w[e] * dis[d];
        atomicAdd(&cnt[d * NBUCK + s / BUCK_DIV], 1);
    }
}

// single-block exclusive scan over n*NBUCK counts -> rowptr[0..total]
// (two-pass: re-reads cnt from global; preproc-only, cost negligible)
__global__ void k_scan(const int* __restrict__ cnt, int* __restrict__ rowptr,
                       int total) {
    __shared__ int part[1024];
    const int PER = 79;  // 1024*79 >= 80000
    int t = threadIdx.x;
    int base = t * PER;
    int s = 0;
    for (int j = 0; j < PER; j++) {
        int idx = base + j;
        if (idx < total) s += cnt[idx];
    }
    part[t] = s;
    __syncthreads();
    for (int off = 1; off < 1024; off <<= 1) {
        int v = part[t];
        int u = (t >= off) ? part[t - off] : 0;
        __syncthreads();
        part[t] = v + u;
        __syncthreads();
    }
    int excl = (t > 0) ? part[t - 1] : 0;
    for (int j = 0; j < PER; j++) {
        int idx = base + j;
        if (idx < total) { rowptr[idx] = excl; excl += cnt[idx]; }
    }
    if (t == 1023) rowptr[total] = part[1023];
}

// pair CSR: {src byte-offset (stride-64 rows), norm bits}, bucket-grouped per dst
__global__ void k_fill(const int* __restrict__ ei, const float* __restrict__ normw,
                       const int* __restrict__ rowptr, int* fill,
                       int2* __restrict__ pr, int E) {
    int e = blockIdx.x * blockDim.x + threadIdx.x;
    if (e < E) {
        int s = ei[e];
        int d = ei[E + e];
        int bk = d * NBUCK + s / BUCK_DIV;
        int pos = atomicAdd(&fill[bk], 1);
        int idx = rowptr[bk] + pos;
        pr[idx] = make_int2(s << 8, __float_as_int(normw[e]));
    }
}

// ---------------- gathers ----------------
// wide single-stream continuation: batch-8 pipelined from offset e.
__device__ __forceinline__ float gather_w_from(const char* __restrict__ tb,
                                               const int2* __restrict__ pr,
                                               int rb, int e, int dg, int lane4,
                                               float agg) {
    for (; e + 8 <= dg; e += 8) {
        int2 p[8]; float v[8];
#pragma unroll
        for (int u = 0; u < 8; u++) p[u] = pr[rb + e + u];
#pragma unroll
        for (int u = 0; u < 8; u++)
            v[u] = *(const float*)(tb + (unsigned)p[u].x + lane4);
#pragma unroll
        for (int u = 0; u < 8; u++)
            agg = fmaf(__int_as_float(p[u].y), v[u], agg);
    }
    if (e < dg) {  // masked batch-8 tail: stays pipelined
        int2 p[8]; float v[8];
#pragma unroll
        for (int u = 0; u < 8; u++) p[u] = pr[(e + u < dg) ? (rb + e + u) : rb];
#pragma unroll
        for (int u = 0; u < 8; u++)
            v[u] = *(const float*)(tb + (unsigned)p[u].x + lane4);
#pragma unroll
        for (int u = 0; u < 8; u++) {
            float w = (e + u < dg) ? __int_as_float(p[u].y) : 0.f;
            agg = fmaf(w, v[u], agg);
        }
    }
    return agg;
}

// dual-stream wide gather: two nodes' edge lists interleaved batch-8/batch-8.
__device__ __forceinline__ void gather_w2(const char* __restrict__ tb,
                                          const int2* __restrict__ pr,
                                          int rb0, int dg0, int rb1, int dg1,
                                          int lane4, float& o0, float& o1) {
    float a0 = 0.f, a1 = 0.f;
    int e0 = 0, e1 = 0;
    while (e0 + 8 <= dg0 && e1 + 8 <= dg1) {
        int2 p0[8], p1[8]; float v0[8], v1[8];
#pragma unroll
        for (int u = 0; u < 8; u++) { p0[u] = pr[rb0 + e0 + u]; p1[u] = pr[rb1 + e1 + u]; }
#pragma unroll
        for (int u = 0; u < 8; u++) {
            v0[u] = *(const float*)(tb + (unsigned)p0[u].x + lane4);
            v1[u] = *(const float*)(tb + (unsigned)p1[u].x + lane4);
        }
#pragma unroll
        for (int u = 0; u < 8; u++) {
            a0 = fmaf(__int_as_float(p0[u].y), v0[u], a0);
            a1 = fmaf(__int_as_float(p1[u].y), v1[u], a1);
        }
        e0 += 8; e1 += 8;
    }
    o0 = gather_w_from(tb, pr, rb0, e0, dg0, lane4, a0);
    o1 = gather_w_from(tb, pr, rb1, e1, dg1, lane4, a1);
}

// narrow (stride-4 float rows): lane = eo*4+lc, 16 edges in parallel, batch-2.
// pair offset is src<<8; stride-4 byte offset = src<<4 = off>>4.
__device__ __forceinline__ float gather_n(const char* __restrict__ tb,
                                          const int2* __restrict__ pr,
                                          int rb, int dg, int lc4, int eo) {
    float agg = 0.f;
    int e = eo;
    for (; e + 32 <= dg; e += 32) {
        int2 p0 = pr[rb + e];
        int2 p1 = pr[rb + e + 16];
        float v0 = *(const float*)(tb + ((unsigned)p0.x >> 4) + lc4);
        float v1 = *(const float*)(tb + ((unsigned)p1.x >> 4) + lc4);
        agg = fmaf(__int_as_float(p0.y), v0, agg);
        agg = fmaf(__int_as_float(p1.y), v1, agg);
    }
    for (; e < dg; e += 16) {
        int2 p = pr[rb + e];
        agg = fmaf(__int_as_float(p.y),
                   *(const float*)(tb + ((unsigned)p.x >> 4) + lc4), agg);
    }
    agg += __shfl_xor(agg, 4);
    agg += __shfl_xor(agg, 8);
    agg += __shfl_xor(agg, 16);
    agg += __shfl_xor(agg, 32);
    return agg;  // channel lc, replicated across eo groups
}

// ---------------- dense (dual-node, W from LDS) ----------------
template <int CI, int CO>
__device__ __forceinline__ void dense2(float& a0, float x0, float& a1, float x1,
                                       const float* sW, int lane) {
#pragma unroll
    for (int c = 0; c < CI; c++) {
        float w;
        if (CO < 64) w = (lane < CO) ? sW[c * CO + lane] : 0.f;
        else         w = sW[c * CO + lane];
        float b0 = __int_as_float(__builtin_amdgcn_readlane(__float_as_int(x0), c));
        float b1 = __int_as_float(__builtin_amdgcn_readlane(__float_as_int(x1), c));
        a0 = fmaf(b0, w, a0);
        a1 = fmaf(b1, w, a1);
    }
}

// ---------------- step kernels: one wave per TWO nodes ----------------
// MODE 1: fused k0+k1  (acc = b + h@W0 + prop(h)@W1, publish T1)
// MODE 2: recurrence   (T2 = 2*prop(T1) - T0, acc += T2@Wk, publish T2)
// LAST 0: store acc + publish; 1: silu -> hout; 2: silu + layer4 sigmoid -> out

template <int CI, int CO, int MODE, int LAST>
__global__ __launch_bounds__(256, 6) void k_wide(
    const int* __restrict__ rowptr, const int2* __restrict__ pr,
    const float* __restrict__ hin,
    const float* __restrict__ t0, const float* __restrict__ t1,
    float* __restrict__ t2, float* __restrict__ accb,
    const float* __restrict__ Wk, const float* __restrict__ bias,
    const float* __restrict__ W4, float* __restrict__ outp)
{
    __shared__ float sW[(MODE == 1 ? 2 : 1) * CI * CO];
    int tid = threadIdx.x;
    const int NW = (MODE == 1 ? 2 : 1) * CI * CO;
    for (int i = tid; i < NW; i += 256) sW[i] = Wk[i];
    __syncthreads();

    int lane = tid & 63;
    int lane4 = lane * 4;
    int node0 = blockIdx.x * 8 + (tid >> 6) * 2;
    int node1 = node0 + 1;
    int rb0 = rowptr[node0 * NBUCK], dg0 = rowptr[(node0 + 1) * NBUCK] - rb0;
    int rb1 = rowptr[node1 * NBUCK], dg1 = rowptr[(node1 + 1) * NBUCK] - rb1;

    float acc0, acc1, t2v0, t2v1;
    if (MODE == 1) {
        float h0 = hin[node0 * 64 + lane];
        float h1 = hin[node1 * 64 + lane];
        float b = (lane < CO) ? bias[lane] : 0.f;
        acc0 = b; acc1 = b;
        dense2<CI, CO>(acc0, h0, acc1, h1, sW, lane);
        gather_w2((const char*)hin, pr, rb0, dg0, rb1, dg1, lane4, t2v0, t2v1);
        dense2<CI, CO>(acc0, t2v0, acc1, t2v1, sW + CI * CO, lane);
    } else {
        acc0 = accb[node0 * 64 + lane];
        acc1 = accb[node1 * 64 + lane];
        float t00 = t0[node0 * 64 + lane];
        float t01 = t0[node1 * 64 + lane];
        float g0, g1;
        gather_w2((const char*)t1, pr, rb0, dg0, rb1, dg1, lane4, g0, g1);
        t2v0 = fmaf(2.f, g0, -t00);
        t2v1 = fmaf(2.f, g1, -t01);
        dense2<CI, CO>(acc0, t2v0, acc1, t2v1, sW, lane);
    }

    if (LAST == 0) {
        accb[node0 * 64 + lane] = acc0;
        accb[node1 * 64 + lane] = acc1;
        t2[node0 * 64 + lane] = t2v0;
        t2[node1 * 64 + lane] = t2v1;
    } else if (LAST == 1) {
        outp[node0 * 64 + lane] = acc0 / (1.f + expf(-acc0));  // silu; lanes>=CO: 0
        outp[node1 * 64 + lane] = acc1 / (1.f + expf(-acc1));
    } else {
        float w4 = (lane < 30) ? W4[lane] : 0.f;
        float h0 = acc0 / (1.f + expf(-acc0));
        float p = h0 * w4;
        p += __shfl_xor(p, 1);
        p += __shfl_xor(p, 2);
        p += __shfl_xor(p, 4);
        p += __shfl_xor(p, 8);
        p += __shfl_xor(p, 16);
        p += __shfl_xor(p, 32);
        if (lane == 0) outp[node0] = 1.f / (1.f + expf(-p));
        float h1 = acc1 / (1.f + expf(-acc1));
        float q = h1 * w4;
        q += __shfl_xor(q, 1);
        q += __shfl_xor(q, 2);
        q += __shfl_xor(q, 4);
        q += __shfl_xor(q, 8);
        q += __shfl_xor(q, 16);
        q += __shfl_xor(q, 32);
        if (lane == 0) outp[node1] = 1.f / (1.f + expf(-q));
    }
}

template <int MODE, int LAST>
__global__ __launch_bounds__(256, 8) void k_narrow(
    const int* __restrict__ rowptr, const int2* __restrict__ pr,
    const float* __restrict__ xin,
    const float* __restrict__ t0, const float* __restrict__ t1,
    float* __restrict__ t2, float* __restrict__ accb,
    const float* __restrict__ Wk, const float* __restrict__ bias,
    float* __restrict__ outp)
{
    __shared__ float sW[(MODE == 1 ? 2 : 1) * 4 * 64];
    int tid = threadIdx.x;
    const int NW = (MODE == 1 ? 2 : 1) * 4 * 64;
    for (int i = tid; i < NW; i += 256) sW[i] = Wk[i];
    __syncthreads();

    int lane = tid & 63;
    int lc = lane & 3, eo = lane >> 2, lc4 = lc * 4;
    int node0 = blockIdx.x * 8 + (tid >> 6) * 2;
    int node1 = node0 + 1;
    int rb0 = rowptr[node0 * NBUCK], dg0 = rowptr[(node0 + 1) * NBUCK] - rb0;
    int rb1 = rowptr[node1 * NBUCK], dg1 = rowptr[(node1 + 1) * NBUCK] - rb1;

    float acc0, acc1, t2v0, t2v1;
    if (MODE == 1) {
        float x0 = xin[node0 * 4 + lc];
        float x1 = xin[node1 * 4 + lc];
        float b = bias[lane];
        acc0 = b; acc1 = b;
        dense2<4, 64>(acc0, x0, acc1, x1, sW, lane);
        t2v0 = gather_n((const char*)xin, pr, rb0, dg0, lc4, eo);
        t2v1 = gather_n((const char*)xin, pr, rb1, dg1, lc4, eo);
        dense2<4, 64>(acc0, t2v0, acc1, t2v1, sW + 4 * 64, lane);
    } else {
        acc0 = accb[node0 * 64 + lane];
        acc1 = accb[node1 * 64 + lane];
        float t00 = t0[node0 * 4 + lc];
        float t01 = t0[node1 * 4 + lc];
        float g0 = gather_n((const char*)t1, pr, rb0, dg0, lc4, eo);
        float g1 = gather_n((const char*)t1, pr, rb1, dg1, lc4, eo);
        t2v0 = fmaf(2.f, g0, -t00);
        t2v1 = fmaf(2.f, g1, -t01);
        dense2<4, 64>(acc0, t2v0, acc1, t2v1, sW, lane);
    }

    if (LAST == 0) {
        accb[node0 * 64 + lane] = acc0;
        accb[node1 * 64 + lane] = acc1;
        if (lane < 4) {
            t2[node0 * 4 + lane] = t2v0;
            t2[node1 * 4 + lane] = t2v1;
        }
    } else {
        outp[node0 * 64 + lane] = acc0 / (1.f + expf(-acc0));
        outp[node1 * 64 + lane] = acc1 / (1.f + expf(-acc1));
    }
}

// ---------------- host ----------------

extern "C" void kernel_launch(void* const* d_in, const int* in_sizes, int n_in,
                              void* d_out, int out_size, void* d_ws, size_t ws_size,
                              hipStream_t stream) {
    const float* x  = (const float*)d_in[0];
    const int*   ei = (const int*)d_in[1];
    const float* ew = (const float*)d_in[2];
    const float* W1 = (const float*)d_in[3];
    const float* b1 = (const float*)d_in[4];
    const float* W2 = (const float*)d_in[5];
    const float* b2 = (const float*)d_in[6];
    const float* W3 = (const float*)d_in[7];
    const float* b3 = (const float*)d_in[8];
    const float* W4 = (const float*)d_in[9];
    float* out = (float*)d_out;

    const int n = N_NODES, E = N_EDGES;

    char* ws = (char*)d_ws;
    size_t off = 0;
    auto alloc = [&](size_t bytes) -> void* {
        void* p = ws + off;
        off += (bytes + 255) & ~(size_t)255;
        return p;
    };
    float* deg    = (float*)alloc(n * 4);                 // becomes dis in-place
    int*   cnt    = (int*)alloc((size_t)n * NBUCK * 4);
    int*   fill   = (int*)alloc((size_t)n * NBUCK * 4);
    int*   rowptr = (int*)alloc(((size_t)n * NBUCK + 8) * 4);
    float* normw  = (float*)alloc((size_t)E * 4);
    int2*  pr     = (int2*)alloc((size_t)E * 8);
    float* t4a  = (float*)alloc(n * 4 * 4);
    float* t4b  = (float*)alloc(n * 4 * 4);
    float* t4c  = (float*)alloc(n * 4 * 4);
    float* tba  = (float*)alloc(n * 64 * 4);
    float* tbb  = (float*)alloc(n * 64 * 4);
    float* tbc  = (float*)alloc(n * 64 * 4);
    float* accb = (float*)alloc(n * 64 * 4);
    float* h1   = (float*)alloc(n * 64 * 4);
    float* h2   = (float*)alloc(n * 64 * 4);
    (void)ws_size; (void)n_in; (void)in_sizes; (void)out_size;

    // ---- preprocessing: degree, norm, src-bucketed dst-sorted pair-CSR ----
    k_init<<<(n * NBUCK + 255) / 256, 256, 0, stream>>>(deg, cnt, fill, n);
    k_deg <<<(E + 255) / 256, 256, 0, stream>>>(ei, ew, deg, E);
    k_dis <<<(n + 255) / 256, 256, 0, stream>>>(deg, n);
    k_norm<<<(E + 255) / 256, 256, 0, stream>>>(ei, ew, deg, normw, cnt, E);
    k_scan<<<1, 1024, 0, stream>>>(cnt, rowptr, n * NBUCK);
    k_fill<<<(E + 255) / 256, 256, 0, stream>>>(ei, normw, rowptr, fill, pr, E);

    const int G = n / 8;  // 1250 blocks x 256 threads, one wave per TWO nodes

    // ---- Layer 1: K=120, 4 -> 64, silu -> h1 ----
    {
        const int K = 120;
        float* tb[3] = {t4a, t4b, t4c};
        k_narrow<1, 0><<<G, 256, 0, stream>>>(rowptr, pr, x, nullptr, nullptr,
                                              tb[1], accb, W1, b1, nullptr);
        for (int k = 2; k < K; k++) {
            const float* t0p = (k == 2) ? x : tb[(k - 2) % 3];
            const float* t1p = tb[(k - 1) % 3];
            const float* Wk = W1 + (size_t)k * 4 * 64;
            if (k < K - 1)
                k_narrow<2, 0><<<G, 256, 0, stream>>>(rowptr, pr, nullptr, t0p, t1p,
                                                      tb[k % 3], accb, Wk, nullptr, nullptr);
            else
                k_narrow<2, 1><<<G, 256, 0, stream>>>(rowptr, pr, nullptr, t0p, t1p,
                                                      nullptr, accb, Wk, nullptr, h1);
        }
    }

    // ---- Layer 2: K=120, 64 -> 60, silu -> h2 ----
    {
        const int K = 120;
        float* tb[3] = {tba, tbb, tbc};
        k_wide<64, 60, 1, 0><<<G, 256, 0, stream>>>(rowptr, pr, h1, nullptr, nullptr,
                                                    tb[1], accb, W2, b2, nullptr, nullptr);
        for (int k = 2; k < K; k++) {
            const float* t0p = (k == 2) ? h1 : tb[(k - 2) % 3];
            const float* t1p = tb[(k - 1) % 3];
            const float* Wk = W2 + (size_t)k * 64 * 60;
            if (k < K - 1)
                k_wide<64, 60, 2, 0><<<G, 256, 0, stream>>>(rowptr, pr, nullptr, t0p, t1p,
                                                            tb[k % 3], accb, Wk, nullptr,
                                                            nullptr, nullptr);
            else
                k_wide<64, 60, 2, 1><<<G, 256, 0, stream>>>(rowptr, pr, nullptr, t0p, t1p,
                                                            nullptr, accb, Wk, nullptr,
                                                            nullptr, h2);
        }
    }

    // ---- Layer 3 (K=20, 60 -> 30, silu) + fused Layer 4 (30 -> 1, sigmoid) ----
    {
        const int K = 20;
        float* tb[3] = {tba, tbb, tbc};
        k_wide<60, 30, 1, 0><<<G, 256, 0, stream>>>(rowptr, pr, h2, nullptr, nullptr,
                                                    tb[1], accb, W3, b3, nullptr, nullptr);
        for (int k = 2; k < K; k++) {
            const float* t0p = (k == 2) ? h2 : tb[(k - 2) % 3];
            const float* t1p = tb[(k - 1) % 3];
            const float* Wk = W3 + (size_t)k * 60 * 30;
            if (k < K - 1)
                k_wide<60, 30, 2, 0><<<G, 256, 0, stream>>>(rowptr, pr, nullptr, t0p, t1p,
                                                            tb[k % 3], accb, Wk, nullptr,
                                                            nullptr, nullptr);
            else
                k_wide<60, 30, 2, 2><<<G, 256, 0, stream>>>(rowptr, pr, nullptr, t0p, t1p,
                                                            nullptr, accb, Wk, nullptr,
                                                            W4, out);
        }
    }
}